// Round 7
// baseline (573.240 us; speedup 1.0000x reference)
//
#include <hip/hip_runtime.h>

typedef _Float16 f16;
typedef __attribute__((ext_vector_type(4))) _Float16 h4v;   // K=16 mfma operand
typedef __attribute__((ext_vector_type(8))) _Float16 h8v;   // paired frag load
typedef __attribute__((ext_vector_type(4))) float f4v;      // 16x16 accumulator

// fp16 weight workspace (elements), K=16 frag-major.
// 128x128: 32 chunks of 512 elems; chunk c=(rt*4+kp): lane*8 + half*4 + j holds
//   W[rt*16+(lane&15)][(kp*2+half)*16 + (lane>>4)*4 + j]   (two frags per 1KB chunk)
// 128x16 (L1, padded from K=8): 8 frags of 256: lane*4+j -> W[fi*16+(lane&15)][(lane>>4)*4+j]
// Ao5 16x128: 4 chunks of 512 like the big ones with rt=0.
#define OFF_WQ  0
#define OFF_WK  2048
#define OFF_WV  4096
#define OFF_AQ1 6144
#define OFF_AK1 22528
#define OFF_AV1 38912
#define OFF_AQ5 55296
#define OFF_AK5 71680
#define OFF_AV5 88064
#define OFF_AO  104448
#define OFF_AO1 120832
#define OFF_AO5 137216
#define WTS_TOTAL 139264

__device__ __forceinline__ f4v mfma_(h4v a, h4v b, f4v c) {
  return __builtin_amdgcn_mfma_f32_16x16x16f16(a, b, c, 0, 0, 0);
}
__device__ __forceinline__ float rcp_(float x) { return __builtin_amdgcn_rcpf(x); }
__device__ __forceinline__ unsigned int pk2(float a, float b) {
  __fp16 __attribute__((ext_vector_type(2))) h2 = __builtin_amdgcn_cvt_pkrtz(a, b);
  return *reinterpret_cast<unsigned int*>(&h2);
}

// XOR-swizzled LDS addressing: pitch 256B (K^T [m][r]) and 128B (V [r][m])
__device__ __forceinline__ f16* swz256(f16* b, int n, int k) {
  int byte = (n << 8) + (k << 1); byte ^= (n & 7) << 4;
  return (f16*)((char*)b + byte);
}
__device__ __forceinline__ const f16* swz256c(const f16* b, int n, int k) {
  int byte = (n << 8) + (k << 1); byte ^= (n & 7) << 4;
  return (const f16*)((const char*)b + byte);
}
__device__ __forceinline__ f16* swz128(f16* b, int r, int m) {
  int byte = (r << 7) + (m << 1); byte ^= (r & 7) << 4;
  return (f16*)((char*)b + byte);
}
__device__ __forceinline__ const f16* swz128c(const f16* b, int r, int m) {
  int byte = (r << 7) + (m << 1); byte ^= (r & 7) << 4;
  return (const f16*)((const char*)b + byte);
}

union pkun { unsigned long long u64; unsigned int u32[2]; h4v h; };

// ACT: 0 sigmoid, 1 silu, 2 none — f32 math (v_rcp), packed to 4 f16 (= h4v / u64)
template<int ACT>
__device__ __forceinline__ pkun pack4act(f4v acc) {
  float v[4];
  #pragma unroll
  for (int j = 0; j < 4; ++j) {
    float t = acc[j];
    if (ACT == 0)      t = rcp_(1.0f + __expf(-t));
    else if (ACT == 1) t = t * rcp_(1.0f + __expf(-t));
    v[j] = t;
  }
  pkun u;
  u.u32[0] = pk2(v[0], v[1]);
  u.u32[1] = pk2(v[2], v[3]);
  return u;
}

__device__ __forceinline__ h4v lo4(h8v p) { return __builtin_shufflevector(p, p, 0, 1, 2, 3); }
__device__ __forceinline__ h4v hi4(h8v p) { return __builtin_shufflevector(p, p, 4, 5, 6, 7); }

// QKV phase: per r-tile rt, Q/K: A=W-frag (row=r), B=X (col=n, regs); V^T: A=X(row=m), B=Wv(col=r).
// Q stays in regs (qreg), K -> Kt[m][r], V -> Vb[r][m].
template<int NF>   // NF = number of K=16 frags (1 for L1, 8 for K=128)
__device__ __forceinline__ void qkv_phase(const f16* __restrict__ Wq,
                                          const f16* __restrict__ Wk,
                                          const f16* __restrict__ Wv,
                                          const h4v* __restrict__ xf,
                                          h4v* __restrict__ qreg,
                                          f16* __restrict__ Kt, f16* __restrict__ Vb,
                                          int lane, int n, int lrow, int lk, int s0)
{
  #pragma unroll
  for (int rt = 0; rt < 8; ++rt) {
    f4v aq = {0.f,0.f,0.f,0.f}, ak = {0.f,0.f,0.f,0.f}, av = {0.f,0.f,0.f,0.f};
    if (NF == 1) {
      h4v fq = *(const h4v*)(Wq + rt * 256 + lane * 4);
      h4v fk = *(const h4v*)(Wk + rt * 256 + lane * 4);
      h4v fv = *(const h4v*)(Wv + rt * 256 + lane * 4);
      aq = mfma_(fq, xf[0], aq);
      ak = mfma_(fk, xf[0], ak);
      av = mfma_(xf[0], fv, av);
    } else {
      #pragma unroll
      for (int kp = 0; kp < NF / 2; ++kp) {
        h8v pq = *(const h8v*)(Wq + (rt * 4 + kp) * 512 + lane * 8);
        h8v pk = *(const h8v*)(Wk + (rt * 4 + kp) * 512 + lane * 8);
        h8v pv = *(const h8v*)(Wv + (rt * 4 + kp) * 512 + lane * 8);
        aq = mfma_(lo4(pq), xf[2 * kp], aq);
        aq = mfma_(hi4(pq), xf[2 * kp + 1], aq);
        ak = mfma_(lo4(pk), xf[2 * kp], ak);
        ak = mfma_(hi4(pk), xf[2 * kp + 1], ak);
        av = mfma_(xf[2 * kp], lo4(pv), av);
        av = mfma_(xf[2 * kp + 1], hi4(pv), av);
      }
    }
    qreg[rt] = pack4act<0>(aq).h;                                   // Q^T[n][r] in regs
    *(unsigned long long*)swz256(Kt, n, rt * 16 + lk * 4) = pack4act<0>(ak).u64;
    *(unsigned long long*)swz128(Vb, rt * 16 + lrow, s0 + lk * 4) = pack4act<0>(av).u64;
  }
}

// Softmax: S^T[m][n] = sum_r K^T[m][r] Q^T[n][r]; A=K (LDS), B=Q (regs). Softmax over m.
__device__ __forceinline__ void softmax_phase(const f16* __restrict__ Kt,
                                              const h4v* __restrict__ qreg,
                                              h4v* __restrict__ preg,
                                              float is, int lrow, int lk)
{
  f4v acc[4];
  #pragma unroll
  for (int mt = 0; mt < 4; ++mt) {
    acc[mt] = (f4v){0.f, 0.f, 0.f, 0.f};
    #pragma unroll
    for (int kr = 0; kr < 8; ++kr) {
      h4v a = *(const h4v*)swz256c(Kt, mt * 16 + lrow, kr * 16 + lk * 4);
      acc[mt] = mfma_(a, qreg[kr], acc[mt]);
    }
  }
  // lane holds S^T[m = mt*16+lk*4+j][n]; reduce 16 regs + lane groups {n, n+16, n+32, n+48}
  float mx = -1e30f;
  #pragma unroll
  for (int mt = 0; mt < 4; ++mt)
    #pragma unroll
    for (int j = 0; j < 4; ++j) { acc[mt][j] *= is; mx = fmaxf(mx, acc[mt][j]); }
  mx = fmaxf(mx, __shfl_xor(mx, 16));
  mx = fmaxf(mx, __shfl_xor(mx, 32));
  float sm = 0.f;
  #pragma unroll
  for (int mt = 0; mt < 4; ++mt)
    #pragma unroll
    for (int j = 0; j < 4; ++j) { acc[mt][j] = __expf(acc[mt][j] - mx); sm += acc[mt][j]; }
  sm += __shfl_xor(sm, 16);
  sm += __shfl_xor(sm, 32);
  const float inv = rcp_(sm);
  #pragma unroll
  for (int mt = 0; mt < 4; ++mt) {
    pkun u;
    u.u32[0] = pk2(acc[mt][0] * inv, acc[mt][1] * inv);
    u.u32[1] = pk2(acc[mt][2] * inv, acc[mt][3] * inv);
    preg[mt] = u.h;                        // P[n][m], k=m on (lk,j) — feeds PV directly
  }
}

// PV: O[r][n] = sum_m V[r][m] P[n][m]; A=V (LDS), B=P (regs). O stays in regs (f16).
__device__ __forceinline__ void pv_phase(const f16* __restrict__ Vb,
                                         const h4v* __restrict__ preg,
                                         h4v* __restrict__ oreg, int lrow, int lk)
{
  #pragma unroll
  for (int rt = 0; rt < 8; ++rt) {
    f4v acc = {0.f, 0.f, 0.f, 0.f};
    #pragma unroll
    for (int km = 0; km < 4; ++km) {
      h4v a = *(const h4v*)swz128c(Vb, rt * 16 + lrow, km * 16 + lk * 4);
      acc = mfma_(a, preg[km], acc);
    }
    oreg[rt] = pack4act<2>(acc).h;
  }
}

// AO: R[s][n] = silu(sum_r Ao[s][r] O[r][n]); A=Ao (global frags), B=O (regs). R -> xf regs.
__device__ __forceinline__ void ao_phase(const f16* __restrict__ Ao,
                                         const h4v* __restrict__ oreg,
                                         h4v* __restrict__ xf, int lane)
{
  #pragma unroll
  for (int st = 0; st < 8; ++st) {
    f4v acc = {0.f, 0.f, 0.f, 0.f};
    #pragma unroll
    for (int kp = 0; kp < 4; ++kp) {
      h8v pa = *(const h8v*)(Ao + (st * 4 + kp) * 512 + lane * 8);
      acc = mfma_(lo4(pa), oreg[2 * kp], acc);
      acc = mfma_(hi4(pa), oreg[2 * kp + 1], acc);
    }
    xf[st] = pack4act<1>(acc).h;
  }
}

__global__ __launch_bounds__(256, 4)
void swarm_attn_mfma(const float* __restrict__ x, const float* __restrict__ L,
                     const f16* __restrict__ wts, float* __restrict__ rch)
{
  __shared__ f16 Kt[64 * 128];   // K^T [m][r] pitch 256B swz (16 KB)
  __shared__ f16 Vb[128 * 64];   // V [r][m] pitch 128B swz (16 KB)
  __shared__ float s_inv;

  const int b = blockIdx.x, tid = threadIdx.x;
  const int w = tid >> 6, lane = tid & 63;
  const int lrow = lane & 15, lk = lane >> 4;
  const int s0 = w * 16;          // this wave's n-strip base
  const int n = s0 + lrow;        // this lane's n (on lane&15 throughout)

  h4v xf[8], qreg[8], preg[4], oreg[8];

  // Layer-1 X fragment: f = lk*4+j, zero-padded f>=8 (K=16)
  #pragma unroll
  for (int j = 0; j < 4; ++j) {
    const int f = lk * 4 + j;
    xf[0][j] = (f < 8) ? (f16)x[(size_t)b * 512 + f * 64 + n] : (f16)0.f;
  }
  if (tid < 64) {
    const float lv = L[(size_t)b * 512 + tid];
    const unsigned long long msk = __ballot(lv >= 1.0f);
    if (tid == 0) s_inv = __frsqrt_rn((float)(__popcll(msk) + 1));
  }

  // -------- Layer 1 (K = 16 padded) --------
  qkv_phase<1>(wts + OFF_WQ, wts + OFF_WK, wts + OFF_WV, xf, qreg, Kt, Vb, lane, n, lrow, lk, s0);
  __syncthreads();
  const float is = s_inv;
  softmax_phase(Kt, qreg, preg, is, lrow, lk);
  pv_phase(Vb, preg, oreg, lrow, lk);
  __syncthreads();
  ao_phase(wts + OFF_AO, oreg, xf, lane);

  // -------- Layer 2 (K = 128) --------
  qkv_phase<8>(wts + OFF_AQ1, wts + OFF_AK1, wts + OFF_AV1, xf, qreg, Kt, Vb, lane, n, lrow, lk, s0);
  __syncthreads();
  softmax_phase(Kt, qreg, preg, is, lrow, lk);
  pv_phase(Vb, preg, oreg, lrow, lk);
  __syncthreads();
  ao_phase(wts + OFF_AO1, oreg, xf, lane);

  // -------- Layer 3 (K = 128) --------
  qkv_phase<8>(wts + OFF_AQ5, wts + OFF_AK5, wts + OFF_AV5, xf, qreg, Kt, Vb, lane, n, lrow, lk, s0);
  __syncthreads();
  softmax_phase(Kt, qreg, preg, is, lrow, lk);
  pv_phase(Vb, preg, oreg, lrow, lk);

  // Final: rch[b][s][n] = silu(Ao5 @ O), s = lk*4+j (one 16-row tile)
  {
    f4v acc = {0.f, 0.f, 0.f, 0.f};
    #pragma unroll
    for (int kp = 0; kp < 4; ++kp) {
      h8v pa = *(const h8v*)(wts + OFF_AO5 + kp * 512 + lane * 8);
      acc = mfma_(lo4(pa), oreg[2 * kp], acc);
      acc = mfma_(hi4(pa), oreg[2 * kp + 1], acc);
    }
    #pragma unroll
    for (int j = 0; j < 4; ++j) {
      float v = acc[j];
      v = v * rcp_(1.0f + __expf(-v));
      rch[(size_t)b * 1024 + (lk * 4 + j) * 64 + n] = v;
    }
  }
}

// Convert weights to fp16, K=16 frag-major layouts (see table at top).
__global__ void conv_wts(const float* Aq, const float* Ak, const float* Av,
                         const float* Aq1, const float* Ak1, const float* Av1,
                         const float* Aq5, const float* Ak5, const float* Av5,
                         const float* Ao, const float* Ao1, const float* Ao5,
                         f16* wts)
{
  const int t = blockIdx.x * 256 + threadIdx.x;
  if (t >= WTS_TOTAL) return;
  float v;
  if (t < 6144) {                       // 3 L1 matrices 128x16 (padded from 8): 8 frags x 256
    const int m = t >> 11, idx = t & 2047;
    const int fi = idx >> 8, rem = idx & 255, lane = rem >> 2, j = rem & 3;
    const int r = fi * 16 + (lane & 15), k = (lane >> 4) * 4 + j;
    const float* W = (m == 0) ? Aq : (m == 1) ? Ak : Av;
    v = (k < 8) ? W[r * 8 + k] : 0.f;
  } else if (t < 137216) {              // 8 matrices 128x128: 32 chunks x 512
    const int m = (t - 6144) >> 14, idx = (t - 6144) & 16383;
    const int c = idx >> 9, rem = idx & 511, lane = rem >> 3, sub = rem & 7;
    const int half = sub >> 2, j = sub & 3;
    const int rt = c >> 2, kk = (c & 3) * 2 + half;
    const int r = rt * 16 + (lane & 15), k = kk * 16 + (lane >> 4) * 4 + j;
    const float* W = (m == 0) ? Aq1 : (m == 1) ? Ak1 : (m == 2) ? Av1 :
                     (m == 3) ? Aq5 : (m == 4) ? Ak5 : (m == 5) ? Av5 :
                     (m == 6) ? Ao : Ao1;
    v = W[r * 128 + k];
  } else {                              // Ao5 16x128: 4 chunks x 512
    const int idx = t - 137216;
    const int c = idx >> 9, rem = idx & 511, lane = rem >> 3, sub = rem & 7;
    const int half = sub >> 2, j = sub & 3;
    const int kk = c * 2 + half;
    const int r = lane & 15, k = kk * 16 + (lane >> 4) * 4 + j;
    v = Ao5[r * 128 + k];
  }
  wts[t] = (f16)v;
}

// Stage A: per swarm, channel-sum M_g (4x64x64) + row/col sums of squares
#define ASTR 65
__global__ __launch_bounds__(256, 1)
void reduce_kernel(const float* __restrict__ rch, float* __restrict__ Mw,
                   float* __restrict__ rsw, float* __restrict__ csw)
{
  __shared__ float Msh[4 * 64 * ASTR];
  const int s = blockIdx.x, t = threadIdx.x;
  for (int e = t; e < 16384; e += 256) {
    const int j = e & 63, i = (e >> 6) & 63, g = e >> 12;
    const float* p = rch + ((size_t)s * 64 + i) * 1024 + (4 * g) * 64 + j;
    const float v = p[0] + p[64] + p[128] + p[192];
    Msh[(g * 64 + i) * ASTR + j] = v;
    Mw[(size_t)s * 16384 + e] = v;        // [s][g][i][j]
  }
  __syncthreads();
  const int g = t >> 6, i = t & 63;
  float r2 = 0.f, c2 = 0.f;
  for (int j = 0; j < 64; ++j) {
    const float a = Msh[(g * 64 + i) * ASTR + j];
    const float bb = Msh[(g * 64 + j) * ASTR + i];
    r2 = fmaf(a, a, r2);
    c2 = fmaf(bb, bb, c2);
  }
  rsw[s * 256 + g * 64 + i] = r2;
  csw[s * 256 + g * 64 + i] = c2;
}

// Stage B: fully-parallel expansion to the 256x256 output per swarm (no rch reads)
__global__ __launch_bounds__(256, 1)
void expand_kernel(const float* __restrict__ Mw, const float* __restrict__ rsw,
                   const float* __restrict__ csw, float* __restrict__ out)
{
  const size_t e = ((size_t)blockIdx.x * 256 + threadIdx.x) * 4;
  const int s = (int)(e >> 16);
  const int rem = (int)(e & 65535);
  const int u = rem >> 8, v0 = rem & 255;
  const int ub = u >> 7, ii = (u & 127) >> 1, p = u & 1;
  const float* Ms = Mw + (size_t)s * 16384;
  float4 o;
  float* po = &o.x;
  #pragma unroll
  for (int c = 0; c < 4; ++c) {
    const int v = v0 + c;
    const int vb = v >> 7, jj = (v & 127) >> 1, q = v & 1;
    float val = 0.f;
    if (u == v) {
      val = rsw[s * 256 + (2 * ub) * 64 + ii] + rsw[s * 256 + (2 * ub + 1) * 64 + ii]
          + csw[s * 256 + ub * 64 + ii] + csw[s * 256 + (2 + ub) * 64 + ii];
    } else if (p == q) {
      const int g = 2 * ub + vb, gp = 2 * vb + ub;
      const float a = Ms[g * 4096 + ii * 64 + jj];
      const float bb = Ms[gp * 4096 + jj * 64 + ii];
      val = -(a * a + bb * bb);
    }
    po[c] = val;
  }
  *(float4*)(out + e) = o;
}

extern "C" void kernel_launch(void* const* d_in, const int* in_sizes, int n_in,
                              void* d_out, int out_size, void* d_ws, size_t ws_size,
                              hipStream_t stream)
{
  const float* x   = (const float*)d_in[0];
  const float* L   = (const float*)d_in[1];
  const float* Aq  = (const float*)d_in[2];
  const float* Ak  = (const float*)d_in[3];
  const float* Av  = (const float*)d_in[4];
  const float* Aq1 = (const float*)d_in[5];
  const float* Ak1 = (const float*)d_in[6];
  const float* Av1 = (const float*)d_in[7];
  const float* Aq5 = (const float*)d_in[8];
  const float* Ak5 = (const float*)d_in[9];
  const float* Av5 = (const float*)d_in[10];
  const float* Ao  = (const float*)d_in[11];
  const float* Ao1 = (const float*)d_in[12];
  const float* Ao5 = (const float*)d_in[13];

  // ws: fp16 weights (278528 B) | Mw 128*16384 f32 | rsw | csw
  f16* wts = (f16*)d_ws;
  float* Mw  = (float*)((char*)d_ws + (size_t)WTS_TOTAL * 2);
  float* rsw = Mw + (size_t)128 * 16384;
  float* csw = rsw + 128 * 256;
  // rch (8192x16x64 f32 = 33.55 MB) staged in d_out; expand_kernel reads only
  // Mw/rsw/csw, so overwriting d_out afterwards is race-free.
  float* rch = (float*)d_out;

  conv_wts<<<(WTS_TOTAL + 255) / 256, 256, 0, stream>>>(Aq, Ak, Av, Aq1, Ak1, Av1,
                                                        Aq5, Ak5, Av5, Ao, Ao1, Ao5, wts);
  swarm_attn_mfma<<<8192, 256, 0, stream>>>(x, L, wts, rch);
  reduce_kernel<<<128, 256, 0, stream>>>(rch, Mw, rsw, csw);
  expand_kernel<<<8192, 256, 0, stream>>>(Mw, rsw, csw, (float*)d_out);
}

// Round 8
// 335.857 us; speedup vs baseline: 1.7068x; 1.7068x over previous
//
#include <hip/hip_runtime.h>

typedef _Float16 f16;
typedef __attribute__((ext_vector_type(8))) _Float16 h8v;   // 8 fp16 = 4 VGPR
typedef __attribute__((ext_vector_type(4))) float f4v;      // 16x16 accumulator
typedef __attribute__((ext_vector_type(16))) float f16acc;  // 32x32 accumulator

// fp16 weight workspace layout (elements) — identical to round 6.
#define OFF_WQ  0
#define OFF_WK  2048
#define OFF_WV  4096
#define OFF_AQ1 6144
#define OFF_AK1 22528
#define OFF_AV1 38912
#define OFF_AQ5 55296
#define OFF_AK5 71680
#define OFF_AV5 88064
#define OFF_AO  104448
#define OFF_AO1 120832
#define OFF_AO5 137216      // Ao5 row-major 16x128
#define WTS_TOTAL 139264

// Padded LDS pitches (f16 elements): rows rotate by 4 banks, offsets are literals.
#define P2 136   // 272 B rows for [64][128] buffers (Xt/Qt/Kt)
#define P1 72    // 144 B rows for [128][64] / [64][64] buffers (Vb/Ps)

__device__ __forceinline__ f4v mfma16_(h8v a, h8v b, f4v c) {
  return __builtin_amdgcn_mfma_f32_16x16x32_f16(a, b, c, 0, 0, 0);
}
__device__ __forceinline__ f16acc mfma32_(h8v a, h8v b, f16acc c) {
  return __builtin_amdgcn_mfma_f32_32x32x16_f16(a, b, c, 0, 0, 0);
}
__device__ __forceinline__ float rcp_(float x) { return __builtin_amdgcn_rcpf(x); }
__device__ __forceinline__ unsigned int pk2(float a, float b) {
  __fp16 __attribute__((ext_vector_type(2))) h2 = __builtin_amdgcn_cvt_pkrtz(a, b);
  return *reinterpret_cast<unsigned int*>(&h2);
}
__device__ __forceinline__ f16acc zero16() {
  f16acc z;
  #pragma unroll
  for (int i = 0; i < 16; ++i) z[i] = 0.f;
  return z;
}

// ACT: 0 sigmoid, 1 silu, 2 none — f32 math (v_rcp), packed to 4 f16
template<int ACT>
__device__ __forceinline__ unsigned long long pack4act(float a, float b, float c, float d) {
  float v[4] = {a, b, c, d};
  #pragma unroll
  for (int j = 0; j < 4; ++j) {
    float t = v[j];
    if (ACT == 0)      t = rcp_(1.0f + __expf(-t));
    else if (ACT == 1) t = t * rcp_(1.0f + __expf(-t));
    v[j] = t;
  }
  union { unsigned long long u64; unsigned int u32[2]; } u;
  u.u32[0] = pk2(v[0], v[1]);
  u.u32[1] = pk2(v[2], v[3]);
  return u.u64;
}

// Fused Q,K,V via 32x32x16. Wave w: (rt = w>>1, ct = w&1). X-frags shared by Q/K/V
// (same reg is B-operand for Q/K and A-operand for V^T). Q^T,K^T -> [n][r] P2;
// V -> [r][m] P1. All sigmoid.
template<int NKK>   // K = NKK*16
__device__ __forceinline__ void qkv_ph(const f16* __restrict__ Wq,
                                       const f16* __restrict__ Wk,
                                       const f16* __restrict__ Wv,
                                       const f16* __restrict__ Xt,
                                       f16* __restrict__ Qt, f16* __restrict__ Kt,
                                       f16* __restrict__ Vb, int w, int lane)
{
  const int l31 = lane & 31, lh = lane >> 5;
  const int rt = w >> 1, ct = w & 1;
  const int xbase = (ct * 32 + l31) * P2 + lh * 8;
  h8v xf[NKK];
  #pragma unroll
  for (int kk = 0; kk < NKK; ++kk)
    xf[kk] = *(const h8v*)(Xt + xbase + kk * 16);
  f16acc aq = zero16(), ak = zero16(), av = zero16();
  #pragma unroll
  for (int kk = 0; kk < NKK; ++kk) {
    const int fo = (rt * NKK + kk) * 512 + lane * 8;
    h8v fq = *(const h8v*)(Wq + fo);
    h8v fk = *(const h8v*)(Wk + fo);
    h8v fv = *(const h8v*)(Wv + fo);
    aq = mfma32_(fq, xf[kk], aq);
    ak = mfma32_(fk, xf[kk], ak);
    av = mfma32_(xf[kk], fv, av);     // V^T = X^T · Av^T
  }
  const int nrow = (ct * 32 + l31) * P2;
  const int vrow = (rt * 32 + l31) * P1 + ct * 32 + lh * 4;
  #pragma unroll
  for (int q = 0; q < 4; ++q) {
    const int rr = rt * 32 + q * 8 + lh * 4;
    *(unsigned long long*)(Qt + nrow + rr) =
        pack4act<0>(aq[4*q], aq[4*q+1], aq[4*q+2], aq[4*q+3]);
    *(unsigned long long*)(Kt + nrow + rr) =
        pack4act<0>(ak[4*q], ak[4*q+1], ak[4*q+2], ak[4*q+3]);
    *(unsigned long long*)(Vb + vrow + q * 8) =
        pack4act<0>(av[4*q], av[4*q+1], av[4*q+2], av[4*q+3]);
  }
}

// Softmax on ALL 8 waves: wave (nst = w&3, mh = w>>2) computes m-half mh of n-strip nst.
// Stats combined via LDS smax/ssum. Contains 2 internal __syncthreads (uniform).
__device__ __forceinline__ void softmax_ph(const f16* __restrict__ Qt,
                                           const f16* __restrict__ Kt,
                                           f16* __restrict__ Ps,
                                           float* __restrict__ smax,
                                           float* __restrict__ ssum,
                                           float is, int w, int lane)
{
  const int lrow = lane & 15, lk = lane >> 4;
  const int nst = w & 3, mh = w >> 2;
  const int n = nst * 16 + lrow;
  h8v bq[4];
  #pragma unroll
  for (int kk = 0; kk < 4; ++kk)
    bq[kk] = *(const h8v*)(Qt + n * P2 + kk * 32 + lk * 8);
  f4v acc[2];
  #pragma unroll
  for (int t = 0; t < 2; ++t) {
    const int mt = mh * 2 + t;
    acc[t] = (f4v){0.f, 0.f, 0.f, 0.f};
    #pragma unroll
    for (int kk = 0; kk < 4; ++kk) {
      h8v a = *(const h8v*)(Kt + (mt * 16 + lrow) * P2 + kk * 32 + lk * 8);
      acc[t] = mfma16_(a, bq[kk], acc[t]);
    }
  }
  float mx = -1e30f;
  #pragma unroll
  for (int t = 0; t < 2; ++t)
    #pragma unroll
    for (int j = 0; j < 4; ++j) { acc[t][j] *= is; mx = fmaxf(mx, acc[t][j]); }
  mx = fmaxf(mx, __shfl_xor(mx, 16));
  mx = fmaxf(mx, __shfl_xor(mx, 32));
  if (lk == 0) smax[mh * 64 + n] = mx;
  __syncthreads();
  const float gmax = fmaxf(smax[n], smax[64 + n]);
  float sm = 0.f;
  #pragma unroll
  for (int t = 0; t < 2; ++t)
    #pragma unroll
    for (int j = 0; j < 4; ++j) { acc[t][j] = __expf(acc[t][j] - gmax); sm += acc[t][j]; }
  sm += __shfl_xor(sm, 16);
  sm += __shfl_xor(sm, 32);
  if (lk == 0) ssum[mh * 64 + n] = sm;
  __syncthreads();
  const float inv = rcp_(ssum[n] + ssum[64 + n]);
  #pragma unroll
  for (int t = 0; t < 2; ++t) {
    const int mt = mh * 2 + t;
    union { unsigned long long u64; unsigned int u32[2]; } u;
    u.u32[0] = pk2(acc[t][0] * inv, acc[t][1] * inv);
    u.u32[1] = pk2(acc[t][2] * inv, acc[t][3] * inv);
    *(unsigned long long*)(Ps + n * P1 + mt * 16 + lk * 4) = u.u64;
  }
}

// O = V @ P^T via 32x32x16, K=64. Output O^T[n][r] (P2), no act.
__device__ __forceinline__ void pv_ph(const f16* __restrict__ Vb,
                                      const f16* __restrict__ Ps,
                                      f16* __restrict__ Ot, int w, int lane)
{
  const int l31 = lane & 31, lh = lane >> 5;
  const int rt = w >> 1, ct = w & 1;
  f16acc acc = zero16();
  #pragma unroll
  for (int kk = 0; kk < 4; ++kk) {
    h8v a = *(const h8v*)(Vb + (rt * 32 + l31) * P1 + kk * 16 + lh * 8);
    h8v b = *(const h8v*)(Ps + (ct * 32 + l31) * P1 + kk * 16 + lh * 8);
    acc = mfma32_(a, b, acc);
  }
  const int nrow = (ct * 32 + l31) * P2;
  #pragma unroll
  for (int q = 0; q < 4; ++q)
    *(unsigned long long*)(Ot + nrow + rt * 32 + q * 8 + lh * 4) =
        pack4act<2>(acc[4*q], acc[4*q+1], acc[4*q+2], acc[4*q+3]);
}

// R = silu(Ao @ O) via 32x32x16, K=128. Output R^T[n][s] (P2) -> Xt.
__device__ __forceinline__ void ao_ph(const f16* __restrict__ Ao,
                                      const f16* __restrict__ Ot,
                                      f16* __restrict__ Rt, int w, int lane)
{
  const int l31 = lane & 31, lh = lane >> 5;
  const int st = w >> 1, ct = w & 1;
  f16acc acc = zero16();
  #pragma unroll
  for (int kk = 0; kk < 8; ++kk) {
    h8v a = *(const h8v*)(Ao + (st * 8 + kk) * 512 + lane * 8);
    h8v b = *(const h8v*)(Ot + (ct * 32 + l31) * P2 + kk * 16 + lh * 8);
    acc = mfma32_(a, b, acc);
  }
  const int nrow = (ct * 32 + l31) * P2;
  #pragma unroll
  for (int q = 0; q < 4; ++q)
    *(unsigned long long*)(Rt + nrow + st * 32 + q * 8 + lh * 4) =
        pack4act<1>(acc[4*q], acc[4*q+1], acc[4*q+2], acc[4*q+3]);
}

// Final: rch[b][s][n] = silu(Ao5(16x128) @ O(128x64)), fp32. Waves 0..3, 16x16 path.
__device__ __forceinline__ void final_ph(const f16* __restrict__ Ao5g,
                                         const f16* __restrict__ Ot,
                                         float* __restrict__ rch_b, int w, int lane)
{
  const int lrow = lane & 15, lk = lane >> 4;
  h8v a[4];
  #pragma unroll
  for (int kk = 0; kk < 4; ++kk)
    a[kk] = *(const h8v*)(Ao5g + lrow * 128 + kk * 32 + lk * 8);
  const int n = 16 * w + lrow;
  f4v acc = {0.f, 0.f, 0.f, 0.f};
  #pragma unroll
  for (int kk = 0; kk < 4; ++kk) {
    h8v b = *(const h8v*)(Ot + n * P2 + kk * 32 + lk * 8);
    acc = mfma16_(a[kk], b, acc);
  }
  #pragma unroll
  for (int j = 0; j < 4; ++j) {
    float v = acc[j];
    v = v * rcp_(1.0f + __expf(-v));
    rch_b[(lk * 4 + j) * 64 + n] = v;
  }
}

__global__ __launch_bounds__(512, 4)
void swarm_attn_mfma(const float* __restrict__ x, const float* __restrict__ L,
                     const f16* __restrict__ wts, float* __restrict__ rch)
{
  __shared__ f16 Xt[64 * P2];    // X^T / R^T [n][k]; Ps aliases this buffer
  __shared__ f16 Qt[64 * P2];    // Q^T [n][r]; reused as O^T after softmax
  __shared__ f16 Kt[64 * P2];    // K^T [m][r]
  __shared__ f16 Vb[128 * P1];   // V [r][m]
  __shared__ float smax[2 * 64];
  __shared__ float ssum[2 * 64];
  __shared__ float s_inv;
  f16* Ps = Xt;                  // P [n][m] pitch P1 (Xt dead during softmax/PV)

  const int b = blockIdx.x;
  const int tid = threadIdx.x;
  const int w = tid >> 6, lane = tid & 63;

  // stage layer-1 X^T [n][f], zero-padded to K=16
  {
    const int n = tid >> 3, c = tid & 7;
    unsigned int val = 0;
    if (c < 4) {
      const float a  = x[(size_t)b * 512 + (2 * c) * 64 + n];
      const float bb = x[(size_t)b * 512 + (2 * c + 1) * 64 + n];
      val = pk2(a, bb);
    }
    *(unsigned int*)(Xt + n * P2 + 2 * c) = val;
  }
  if (w == 0) {
    const float lv = L[(size_t)b * 512 + lane];
    const unsigned long long msk = __ballot(lv >= 1.0f);
    if (lane == 0) s_inv = __frsqrt_rn((float)(__popcll(msk) + 1));
  }
  __syncthreads();
  const float is = s_inv;

  // -------- Layer 1 (K = 16 padded) --------
  qkv_ph<1>(wts + OFF_WQ, wts + OFF_WK, wts + OFF_WV, Xt, Qt, Kt, Vb, w, lane);
  __syncthreads();
  softmax_ph(Qt, Kt, Ps, smax, ssum, is, w, lane);
  __syncthreads();
  pv_ph(Vb, Ps, Qt, w, lane);                 // O^T -> Qt
  __syncthreads();
  ao_ph(wts + OFF_AO, Qt, Xt, w, lane);       // R^T -> Xt
  __syncthreads();

  // -------- Layer 2 (K = 128) --------
  qkv_ph<8>(wts + OFF_AQ1, wts + OFF_AK1, wts + OFF_AV1, Xt, Qt, Kt, Vb, w, lane);
  __syncthreads();
  softmax_ph(Qt, Kt, Ps, smax, ssum, is, w, lane);
  __syncthreads();
  pv_ph(Vb, Ps, Qt, w, lane);
  __syncthreads();
  ao_ph(wts + OFF_AO1, Qt, Xt, w, lane);
  __syncthreads();

  // -------- Layer 3 (K = 128) --------
  qkv_ph<8>(wts + OFF_AQ5, wts + OFF_AK5, wts + OFF_AV5, Xt, Qt, Kt, Vb, w, lane);
  __syncthreads();
  softmax_ph(Qt, Kt, Ps, smax, ssum, is, w, lane);
  __syncthreads();
  pv_ph(Vb, Ps, Qt, w, lane);
  __syncthreads();
  if (w < 4) final_ph(wts + OFF_AO5, Qt, rch + (size_t)b * 1024, w, lane);
}

// Convert weights to fp16: frag-major (identical to round 6).
__global__ void conv_wts(const float* Aq, const float* Ak, const float* Av,
                         const float* Aq1, const float* Ak1, const float* Av1,
                         const float* Aq5, const float* Ak5, const float* Av5,
                         const float* Ao, const float* Ao1, const float* Ao5,
                         f16* wts)
{
  const int t = blockIdx.x * 256 + threadIdx.x;
  if (t >= WTS_TOTAL) return;
  float v;
  if (t < 6144) {                       // L1: 128x16 (padded from 8), 4 frags x 512
    const int m = t >> 11, idx = t & 2047;
    const int fi = idx >> 9, rem = idx & 511, lane = rem >> 3, j = rem & 7;
    const int r = fi * 32 + (lane & 31), k = (lane >> 5) * 8 + j;
    const float* W = (m == 0) ? Aq : (m == 1) ? Ak : Av;
    v = (k < 8) ? W[r * 8 + k] : 0.f;
  } else if (t < 137216) {              // 8 matrices 128x128, 32 frags each
    const int m = (t - 6144) >> 14, idx = (t - 6144) & 16383;
    const int fi = idx >> 9, rem = idx & 511, lane = rem >> 3, j = rem & 7;
    const int rt = fi >> 3, kk = fi & 7;
    const int r = rt * 32 + (lane & 31), k = kk * 16 + (lane >> 5) * 8 + j;
    const float* W = (m == 0) ? Aq1 : (m == 1) ? Ak1 : (m == 2) ? Av1 :
                     (m == 3) ? Aq5 : (m == 4) ? Ak5 : (m == 5) ? Av5 :
                     (m == 6) ? Ao : Ao1;
    v = W[r * 128 + k];
  } else {
    v = Ao5[t - 137216];
  }
  wts[t] = (f16)v;
}

// Stage A: per swarm, channel-sum M_g (4x64x64) + row/col sums of squares
#define ASTR 65
__global__ __launch_bounds__(256, 1)
void reduce_kernel(const float* __restrict__ rch, float* __restrict__ Mw,
                   float* __restrict__ rsw, float* __restrict__ csw)
{
  __shared__ float Msh[4 * 64 * ASTR];
  const int s = blockIdx.x, t = threadIdx.x;
  for (int e = t; e < 16384; e += 256) {
    const int j = e & 63, i = (e >> 6) & 63, g = e >> 12;
    const float* p = rch + ((size_t)s * 64 + i) * 1024 + (4 * g) * 64 + j;
    const float v = p[0] + p[64] + p[128] + p[192];
    Msh[(g * 64 + i) * ASTR + j] = v;
    Mw[(size_t)s * 16384 + e] = v;        // [s][g][i][j]
  }
  __syncthreads();
  const int g = t >> 6, i = t & 63;
  float r2 = 0.f, c2 = 0.f;
  for (int j = 0; j < 64; ++j) {
    const float a = Msh[(g * 64 + i) * ASTR + j];
    const float bb = Msh[(g * 64 + j) * ASTR + i];
    r2 = fmaf(a, a, r2);
    c2 = fmaf(bb, bb, c2);
  }
  rsw[s * 256 + g * 64 + i] = r2;
  csw[s * 256 + g * 64 + i] = c2;
}

// Stage B: fully-parallel expansion to the 256x256 output per swarm (no rch reads)
__global__ __launch_bounds__(256, 1)
void expand_kernel(const float* __restrict__ Mw, const float* __restrict__ rsw,
                   const float* __restrict__ csw, float* __restrict__ out)
{
  const size_t e = ((size_t)blockIdx.x * 256 + threadIdx.x) * 4;
  const int s = (int)(e >> 16);
  const int rem = (int)(e & 65535);
  const int u = rem >> 8, v0 = rem & 255;
  const int ub = u >> 7, ii = (u & 127) >> 1, p = u & 1;
  const float* Ms = Mw + (size_t)s * 16384;
  float4 o;
  float* po = &o.x;
  #pragma unroll
  for (int c = 0; c < 4; ++c) {
    const int v = v0 + c;
    const int vb = v >> 7, jj = (v & 127) >> 1, q = v & 1;
    float val = 0.f;
    if (u == v) {
      val = rsw[s * 256 + (2 * ub) * 64 + ii] + rsw[s * 256 + (2 * ub + 1) * 64 + ii]
          + csw[s * 256 + ub * 64 + ii] + csw[s * 256 + (2 + ub) * 64 + ii];
    } else if (p == q) {
      const int g = 2 * ub + vb, gp = 2 * vb + ub;
      const float a = Ms[g * 4096 + ii * 64 + jj];
      const float bb = Ms[gp * 4096 + jj * 64 + ii];
      val = -(a * a + bb * bb);
    }
    po[c] = val;
  }
  *(float4*)(out + e) = o;
}

extern "C" void kernel_launch(void* const* d_in, const int* in_sizes, int n_in,
                              void* d_out, int out_size, void* d_ws, size_t ws_size,
                              hipStream_t stream)
{
  const float* x   = (const float*)d_in[0];
  const float* L   = (const float*)d_in[1];
  const float* Aq  = (const float*)d_in[2];
  const float* Ak  = (const float*)d_in[3];
  const float* Av  = (const float*)d_in[4];
  const float* Aq1 = (const float*)d_in[5];
  const float* Ak1 = (const float*)d_in[6];
  const float* Av1 = (const float*)d_in[7];
  const float* Aq5 = (const float*)d_in[8];
  const float* Ak5 = (const float*)d_in[9];
  const float* Av5 = (const float*)d_in[10];
  const float* Ao  = (const float*)d_in[11];
  const float* Ao1 = (const float*)d_in[12];
  const float* Ao5 = (const float*)d_in[13];

  // ws: fp16 weights (278528 B) | Mw 128*16384 f32 | rsw | csw
  f16* wts = (f16*)d_ws;
  float* Mw  = (float*)((char*)d_ws + (size_t)WTS_TOTAL * 2);
  float* rsw = Mw + (size_t)128 * 16384;
  float* csw = rsw + 128 * 256;
  // rch (8192x16x64 f32 = 33.55 MB) staged in d_out; expand_kernel reads only
  // Mw/rsw/csw, so overwriting d_out afterwards is race-free.
  float* rch = (float*)d_out;

  conv_wts<<<(WTS_TOTAL + 255) / 256, 256, 0, stream>>>(Aq, Ak, Av, Aq1, Ak1, Av1,
                                                        Aq5, Ak5, Av5, Ao, Ao1, Ao5, wts);
  swarm_attn_mfma<<<8192, 512, 0, stream>>>(x, L, wts, rch);
  reduce_kernel<<<128, 256, 0, stream>>>(rch, Mw, rsw, csw);
  expand_kernel<<<8192, 256, 0, stream>>>(Mw, rsw, csw, (float*)d_out);
}